// Round 17
// baseline (72.412 us; speedup 1.0000x reference)
//
#include <hip/hip_runtime.h>
#include <hip/hip_fp16.h>

#define NPROJ  256
#define NDET   384
#define NS     256
#define TW     258                 // texture entries per row (uy,ux in [0,258))
#define TN     (TW * TW)           // 66564 entries (16 B each, both batches)
#define NRAY   (NPROJ * NDET)      // rays per batch
#define TPB    256

typedef _Float16 hvec2 __attribute__((ext_vector_type(2)));

// vertical-pair value: VP(uy,ux) = half2{ P(uy,ux), P(uy+1,ux) },
// P(py,px) = img[py-1][px-1], zero outside (verified R10-R16 builder).
__device__ __forceinline__ uint vp_pack(const float* im, int uy, int ux) {
    int x = ux - 1;
    if ((unsigned)x >= 256u) return 0u;
    float v0 = ((unsigned)(uy - 1) < 256u) ? im[((uy - 1) << 8) + x] : 0.0f;
    float v1 = ((unsigned)uy       < 256u) ? im[(uy << 8) + x]       : 0.0f;
    __half2 h2 = __floats2half2_rn(v0, v1);
    return *reinterpret_cast<uint*>(&h2);
}

// Batch-paired quad texture (verified R15/R16): T[uy*TW+ux] = uint4{
//   b0 VP(uy,ux), b0 VP(uy,ux+1), b1 VP(uy,ux), b1 VP(uy,ux+1) }.
__global__ void quad_build(const float* __restrict__ src, uint4* __restrict__ dst) {
    int e = blockIdx.x * blockDim.x + threadIdx.x;     // over TN
    if (e >= TN) return;
    int uy = e / TW;
    int ux = e - uy * TW;
    const float* im0 = src;
    const float* im1 = src + (1 << 16);
    uint4 q;
    q.x = vp_pack(im0, uy, ux);
    q.y = vp_pack(im0, uy, ux + 1);
    q.z = vp_pack(im1, uy, ux);
    q.w = vp_pack(im1, uy, ux + 1);
    dst[e] = q;
}

// Footprint-compacted (8 det x 8 slots, R14) + batch-paired (R15) + 4-deep
// MLP: each lane handles samples s, s+8, s+16, s+24 per iteration — four 16B
// gathers in flight. Tail samples masked by weight-zeroing (R13/R16 technique).
__global__ __launch_bounds__(TPB) void fanproj_kernel(const uint4* __restrict__ T,
                                                      float* __restrict__ out) {
    int tid   = threadIdx.x;
    int lane  = tid & 63;
    int wv    = tid >> 6;
    int wrp0  = (blockIdx.x << 5) + (wv << 3);         // 32 ray-pairs/block
    int slot  = lane >> 3;                             // 0..7 sample phase
    int rp    = wrp0 + (lane & 7);                     // p*D + d  (pair id)

    int d = rp % NDET;
    int p = rp / NDET;                                 // in [0, NPROJ)

    const float dt = 1.4142135623730951f;              // diag / NS = sqrt(2)
    const float t0 = 219.68777079743137f;              // SID - diag/2 + 0.5*dt

    float theta = (float)p * (6.283185307179586f / (float)NPROJ);
    float st, ct;
    __sincosf(theta, &st, &ct);

    float srcx = -400.0f * ct;
    float srcy = -400.0f * st;
    float off  = ((float)d - 191.5f) * 1.2f;
    float rx   = fmaf(800.0f, ct, -off * st);
    float ry   = fmaf(800.0f, st,  off * ct);
    float n2   = rx * rx + ry * ry;
    float rn   = rsqrtf(n2);
    rn = rn * (1.5f - 0.5f * n2 * rn * rn);            // one Newton step
    rx *= rn;
    ry *= rn;

    // texture coords: X(s)=bxu+s*sx, Y(s)=byu+s*sy, footprint valid in [0,257)
    float bxu = fmaf(t0, rx, srcx) + 128.5f;
    float byu = fmaf(t0, ry, srcy) + 128.5f;
    float sx  = dt * rx;
    float sy  = dt * ry;

    // guard-free interval, EPS-shrunk (verified R8-R16); same for both batches
    const float EPS = 2e-3f;
    float sxs = (fabsf(sx) < 1e-9f) ? copysignf(1e-9f, sx) : sx;
    float sys = (fabsf(sy) < 1e-9f) ? copysignf(1e-9f, sy) : sy;
    float isx = 1.0f / sxs;
    float isy = 1.0f / sys;
    float ax0 = (0.0f - bxu) * isx, ax1 = (257.0f - bxu) * isx;
    float ay0 = (0.0f - byu) * isy, ay1 = (257.0f - byu) * isy;
    float lof = fmaxf(fminf(ax0, ax1), fminf(ay0, ay1)) + EPS;
    float hif = fminf(fmaxf(ax0, ax1), fmaxf(ay0, ay1)) - EPS;
    lof = fminf(fmaxf(lof, -1.0f), 300.0f);
    hif = fminf(fmaxf(hif, -1.0f), 300.0f);
    int slo = max(0,      (int)ceilf(lof));
    int shi = min(NS - 1, (int)floorf(hif));

    int s0  = slo + slot;
    int rem = shi - s0;                                // >=0: sample A valid
    float sf = (float)s0;
    float accA0 = 0.0f, accA1 = 0.0f;                  // chains A/C
    float accB0 = 0.0f, accB1 = 0.0f;                  // chains B/D

    // per-sample address+weight prep (clamped; tail handled by weight mask)
#define PREP(K, SF)                                                           \
    float X##K = fmaf((SF), sx, bxu);                                         \
    float Y##K = fmaf((SF), sy, byu);                                         \
    float xf##K = floorf(X##K), yf##K = floorf(Y##K);                         \
    float wx##K = X##K - xf##K, wy##K = Y##K - yf##K;                         \
    float aF##K = fmaf(yf##K, 258.0f, xf##K);                                 \
    aF##K = fminf(fmaxf(aF##K, 0.0f), 66563.0f);                              \
    int ai##K = (int)aF##K;

    // consume one 16B entry into the two batch accumulators; MASK==0 -> no-op
#define CONSUME(K, Q, A0, A1, VALID)                                          \
    {                                                                         \
        uint hwb##K = __builtin_bit_cast(uint,                                \
            __builtin_amdgcn_cvt_pkrtz(1.0f - wy##K, wy##K));                 \
        hwb##K = (VALID) ? hwb##K : 0u;                                       \
        hvec2 hw##K = __builtin_bit_cast(hvec2, hwb##K);                      \
        float c0 = __builtin_amdgcn_fdot2(__builtin_bit_cast(hvec2, (Q).x),   \
                                          hw##K, 0.0f, false);                \
        float c1 = __builtin_amdgcn_fdot2(__builtin_bit_cast(hvec2, (Q).y),   \
                                          hw##K, 0.0f, false);                \
        A0 = fmaf(wx##K, c1 - c0, A0 + c0);                                   \
        float c2 = __builtin_amdgcn_fdot2(__builtin_bit_cast(hvec2, (Q).z),   \
                                          hw##K, 0.0f, false);                \
        float c3 = __builtin_amdgcn_fdot2(__builtin_bit_cast(hvec2, (Q).w),   \
                                          hw##K, 0.0f, false);                \
        A1 = fmaf(wx##K, c3 - c2, A1 + c2);                                   \
    }

    while (rem >= 0) {
        PREP(A, sf)
        PREP(B, sf + 8.0f)
        PREP(C, sf + 16.0f)
        PREP(D, sf + 24.0f)
        sf += 32.0f;

        uint4 qA = T[aiA];                             // 4 x 16B gathers in flight
        uint4 qB = T[aiB];
        uint4 qC = T[aiC];
        uint4 qD = T[aiD];

        CONSUME(A, qA, accA0, accA1, true)             // rem>=0 guaranteed
        CONSUME(B, qB, accB0, accB1, rem >= 8)
        CONSUME(C, qC, accA0, accA1, rem >= 16)
        CONSUME(D, qD, accB0, accB1, rem >= 24)

        rem -= 32;
    }
#undef PREP
#undef CONSUME

    float acc0 = accA0 + accB0;
    float acc1 = accA1 + accB1;

    // sum the 8 slot-partials (lanes sharing lane&7 differ in bits 3..5)
    acc0 += __shfl_xor(acc0, 8,  64);
    acc0 += __shfl_xor(acc0, 16, 64);
    acc0 += __shfl_xor(acc0, 32, 64);
    acc1 += __shfl_xor(acc1, 8,  64);
    acc1 += __shfl_xor(acc1, 16, 64);
    acc1 += __shfl_xor(acc1, 32, 64);
    if (slot == 0) {
        out[rp]        = acc0 * dt;                    // batch 0
        out[rp + NRAY] = acc1 * dt;                    // batch 1
    }
}

extern "C" void kernel_launch(void* const* d_in, const int* in_sizes, int n_in,
                              void* d_out, int out_size, void* d_ws, size_t ws_size,
                              hipStream_t stream) {
    const float* x = (const float*)d_in[0];
    float* out     = (float*)d_out;
    uint4* T       = (uint4*)d_ws;                     // TN*16 B = 1.07 MB

    quad_build<<<(TN + 255) / 256, 256, 0, stream>>>(x, T);

    // 3072 blocks x 256 threads: 32 ray-pairs/block x 3072 = 98304 pairs
    fanproj_kernel<<<3072, TPB, 0, stream>>>(T, out);
}